// Round 2
// baseline (110.847 us; speedup 1.0000x reference)
//
#include <hip/hip_runtime.h>
#include <hip/hip_fp16.h>

// DeformConv2d: B=16, Cin=64, Cout=64, H=W=64, K=3, stride=1, pad=1, dil=1
// Round 18: stage-count collapse. R17 (counted-drain pipeline) was NEUTRAL ->
// the stall is the 11-stage barrier-lockstep structure, not load latency.
// Split the serial chain across launches:
//   prep    : NHWC-f16 x copy + tap-major weights (unchanged, proven)
//   offs_k  : phase A (offset conv, MFMA) + geometry -> packed grec to ws
//   dcn_main: grec -> LDS (coalesced), single-buffer 9-tap im2col staging
//             (no inter-tap barriers), ONE barrier, straight 18-step MFMA.
// Arithmetic order identical to R14/R17 -> bit-identical output.

#define KOFF 18
#define CTS  136           // colsT stride in halfs (offs_k, 2-tap dbuf)
#define CS9  584           // cols stride in halfs (dcn_main, 9 taps + 8 pad)

#define W2T_HALFS    (18 * 64 * 32)     // [i][64co][32kl], k' = tap*64+cin
#define WOFF2T_HALFS (18 * 32 * 32)     // [i][32co][32kl]
#define W2T_BYTES    (W2T_HALFS * 2)    // 73728
#define WOFF2T_OFF   W2T_BYTES
#define X_OFF        (W2T_BYTES + WOFF2T_HALFS * 2)   // 110592 (16B aligned)
#define XH_BYTES     (16 * 64 * 64 * 64 * 2)          // 8388608
#define GM_OFF       (X_OFF + XH_BYTES)               // 8499200
#define GM_BYTES     (2048 * 288 * 4)                 // 2359296
#define GW_OFF       (GM_OFF + GM_BYTES)              // 10858496
#define GW_BYTES     (2048 * 288 * 8)                 // 4718592
#define WS_NEED      (GW_OFF + GW_BYTES)              // 15577088

typedef _Float16 half8 __attribute__((ext_vector_type(8)));
typedef float floatx4 __attribute__((ext_vector_type(4)));

union H8 { half8 v; __half2 h2[4]; uint4 u; };

// ---------------------------------------------------------------------------
// prep: blocks [0,1024): LDS-tiled transpose of one (b,y) plane (coalesced
// both sides). blocks [1024,1240): weight repack (tap-major f16).
__global__ void prep(const float* __restrict__ x,
                     const float* __restrict__ w_dcn,
                     const float* __restrict__ w_off,
                     _Float16* __restrict__ w2t,
                     _Float16* __restrict__ woff2t,
                     _Float16* __restrict__ xh) {
    const int bi = blockIdx.x;
    const int t  = threadIdx.x;
    if (bi < 1024) {
        const int b = bi >> 6, y = bi & 63;
        __shared__ __align__(16) _Float16 tile[64 * 72];
        const int xx = t & 63;
        const int c4 = t >> 6;
        const float* xp = x + (((size_t)b * 64) * 64 + y) * 64;
#pragma unroll
        for (int p = 0; p < 16; ++p) {
            int cin = p * 4 + c4;
            tile[xx * 72 + cin] = (_Float16)xp[(size_t)cin * 4096 + xx];
        }
        __syncthreads();
        const int oct = t & 7;
        const int xl  = t >> 3;
        _Float16* op = xh + ((((size_t)b * 64 + y) * 64) << 6);
#pragma unroll
        for (int p = 0; p < 2; ++p) {
            int xr = p * 32 + xl;
            half8 v = *(const half8*)&tile[xr * 72 + oct * 8];
            *(half8*)&op[(size_t)xr * 64 + oct * 8] = v;
        }
    } else {
        int e = (bi - 1024) * 256 + t;
        if (e < W2T_HALFS) {
            int kl = e & 31, co = (e >> 5) & 63, i = e >> 11;
            int tap = i >> 1, cin = (i & 1) * 32 + kl;
            w2t[e] = (_Float16)w_dcn[co * 576 + cin * 9 + tap];
        } else {
            int e2 = e - W2T_HALFS;
            int kl = e2 & 31, co = (e2 >> 5) & 31, i = e2 >> 10;
            int tap = i >> 1, cin = (i & 1) * 32 + kl;
            woff2t[e2] = (co < KOFF) ? (_Float16)w_off[co * 576 + cin * 9 + tap]
                                     : (_Float16)0.f;
        }
    }
}

// ---------------------------------------------------------------------------
// offs_k: offset conv (MFMA, tap-pair dbuf — R14-proven) + geometry records,
// written to global ws. Small LDS, high occupancy.
__launch_bounds__(256, 4)
__global__ void offs_k(const _Float16* __restrict__ xh,
                       const _Float16* __restrict__ woff2t,
                       const float* __restrict__ b_off,
                       unsigned int* __restrict__ gm,
                       uint2* __restrict__ gw) {
    const int bid = blockIdx.x;                 // 0..2047
    const int s   = bid >> 3;
    const int b   = ((bid & 7) << 1) | (s >> 7);
    const int ho  = (s >> 1) & 63;
    const int hlf = s & 1;
    const int t    = threadIdx.x;
    const int lane = t & 63;
    const int wid  = __builtin_amdgcn_readfirstlane(t >> 6);
    const int r    = lane & 15;
    const int q    = lane >> 4;
    const int gpx  = t >> 3;
    const int oct  = t & 7;
    const int pxg  = hlf * 32;

    __shared__ __align__(16) _Float16 colsT[2][32 * CTS];   // 17408 B
    __shared__ __align__(16) float    offlds[KOFF * 32];    // 2304 B

    const _Float16* xb = xh + ((size_t)b << 18);

    {
        floatx4 am = {0.f, 0.f, 0.f, 0.f};
        const int m = wid & 1, n = wid >> 1;

        auto loadS = [&](int tap) -> half8 {
            const int dy = tap / 3, dxk = tap - dy * 3;
            const int y  = ho + dy - 1;
            const int xc = pxg + gpx + dxk - 1;
            half8 v = {};
            if (((unsigned)y < 64u) && ((unsigned)xc < 64u))
                v = *(const half8*)&xb[(((size_t)y * 64 + xc) << 6) + oct * 8];
            return v;
        };
        auto loadWA = [&](int i) -> half8 {
            return *(const half8*)&woff2t[i * 1024 + (m * 16 + r) * 32 + q * 8];
        };

        {
            half8 s0 = loadS(0), s1 = loadS(1);
            *(half8*)&colsT[0][gpx * CTS + oct * 8]      = s0;
            *(half8*)&colsT[0][gpx * CTS + 64 + oct * 8] = s1;
        }
        __syncthreads();
#pragma unroll
        for (int p = 0; p < 5; ++p) {
            half8 sn0, sn1;
            if (p < 4) {
                sn0 = loadS(2 * p + 2);
                if (p < 3) sn1 = loadS(2 * p + 3);
            }
            const int nkg = (p < 4) ? 4 : 2;
#pragma unroll
            for (int kg = 0; kg < 4; ++kg) {
                if (kg < nkg) {
                    half8 a  = loadWA(4 * p + kg);
                    half8 bf = *(const half8*)&colsT[p & 1][(n * 16 + r) * CTS
                                                            + kg * 32 + q * 8];
                    am = __builtin_amdgcn_mfma_f32_16x16x32_f16(a, bf, am, 0, 0, 0);
                }
            }
            if (p < 4) {
                *(half8*)&colsT[(p + 1) & 1][gpx * CTS + oct * 8] = sn0;
                if (p < 3)
                    *(half8*)&colsT[(p + 1) & 1][gpx * CTS + 64 + oct * 8] = sn1;
                __syncthreads();
            }
        }
#pragma unroll
        for (int reg = 0; reg < 4; ++reg) {
            int co = m * 16 + q * 4 + reg;
            if (co < KOFF)
                offlds[co * 32 + n * 16 + r] = am[reg] + b_off[co];
        }
    }
    __syncthreads();

    // geometry records -> global (R9-proven encoding)
    for (int e = t; e < 9 * 32; e += 256) {
        int tap = e >> 5, px = e & 31;
        float offy = offlds[(2 * tap) * 32 + px];
        float offx = offlds[(2 * tap + 1) * 32 + px];
        float py  = offy + (float)(tap / 3) + (float)(ho - 1);
        float pxf = offx + (float)(tap % 3) + (float)(pxg + px - 1);
        float fy = floorf(py), fx = floorf(pxf);
        int y0 = (int)fy, x0 = (int)fx;
        float wy1 = py - fy, wx1 = pxf - fx;
        float wy0 = 1.f - wy1, wx0 = 1.f - wx1;
        bool y0ok = ((unsigned)y0 < 64u);
        bool x0ok = ((unsigned)x0 < 64u);
        bool y1ok = ((unsigned)(y0 + 1) < 64u);
        bool x1ok = ((unsigned)(x0 + 1) < 64u);
        float w00 = (y0ok && x0ok) ? wy0 * wx0 : 0.f;
        float w01 = (y0ok && x1ok) ? wy0 * wx1 : 0.f;
        float w10 = (y1ok && x0ok) ? wy1 * wx0 : 0.f;
        float w11 = (y1ok && x1ok) ? wy1 * wx1 : 0.f;
        int yc0 = min(max(y0, 0), 63);
        int xc0 = min(max(x0, 0), 63);
        int yc1 = min(max(y0 + 1, 0), 63);
        int xc1 = min(max(x0 + 1, 0), 63);
        union { __half2 h; unsigned u; } c0, c1;
        c0.h = __floats2half2_rn(w00, w01);
        c1.h = __floats2half2_rn(w10, w11);
        unsigned meta = (unsigned)(yc0 * 64 + xc0)
                      | ((unsigned)(xc1 - xc0) << 12)
                      | ((unsigned)(yc1 - yc0) << 13);
        gm[(size_t)bid * 288 + e] = meta;
        gw[(size_t)bid * 288 + e] = make_uint2(c0.u, c1.u);
    }
}

// ---------------------------------------------------------------------------
// dcn_main v2: 2 barriers total. grec -> LDS, single-buffer 9-tap staging
// (taps write disjoint columns, no sync), one barrier, straight MFMA loop.
__launch_bounds__(256, 4)
__global__ void dcn_main(const _Float16* __restrict__ xh,
                         const _Float16* __restrict__ w2t,
                         const unsigned int* __restrict__ gm,
                         const uint2* __restrict__ gw,
                         const float* __restrict__ b_dcn,
                         float* __restrict__ out) {
    const int bid = blockIdx.x;                 // 0..2047
    const int s   = bid >> 3;
    const int b   = ((bid & 7) << 1) | (s >> 7);
    const int ho  = (s >> 1) & 63;
    const int hlf = s & 1;
    const int t    = threadIdx.x;
    const int lane = t & 63;
    const int wid  = __builtin_amdgcn_readfirstlane(t >> 6);
    const int r    = lane & 15;
    const int q    = lane >> 4;
    const int gpx  = t >> 3;                    // 0..31 gather pixel
    const int oct  = t & 7;                     // 8-cin octet
    const int pxg  = hlf * 32;

    __shared__ __align__(16) _Float16 cols[32 * CS9];       // 37376 B
    __shared__ __align__(16) uint2        gwL[288];         // 2304 B
    __shared__ __align__(16) unsigned int gmL[288];         // 1152 B
    // total 40832 B <= 40960 -> 4 blocks/CU

    const _Float16* xb = xh + ((size_t)b << 18);
    const char* xpb = (const char*)xb;

    // coalesced grec load
    {
        const unsigned int* gmp = gm + (size_t)bid * 288;
        const uint2*        gwp = gw + (size_t)bid * 288;
        gmL[t] = gmp[t];
        gwL[t] = gwp[t];
        if (t < 32) {
            gmL[256 + t] = gmp[256 + t];
            gwL[256 + t] = gwp[256 + t];
        }
    }
    __syncthreads();

    // ---------------- single-buffer 9-tap staging (no barriers) ----------
    struct GP { H8 v[8]; unsigned wy0, wz0, wy1, wz1; };

    auto loadPair = [&](int p) -> GP {
        GP g;
#pragma unroll
        for (int l = 0; l < 2; ++l) {
            int tap = 2 * p + l;
            if (tap < 9) {
                unsigned meta = gmL[tap * 32 + gpx];
                uint2    w    = gwL[tap * 32 + gpx];
                unsigned a00 = (meta & 0xfffu) * 128u + (unsigned)oct * 16u;
                unsigned dx128  = ((meta >> 12) & 1u) * 128u;
                unsigned dy8192 = ((meta >> 13) & 1u) * 8192u;
                g.v[4 * l + 0].v = *(const half8*)(xpb + a00);
                g.v[4 * l + 1].v = *(const half8*)(xpb + a00 + dx128);
                g.v[4 * l + 2].v = *(const half8*)(xpb + a00 + dy8192);
                g.v[4 * l + 3].v = *(const half8*)(xpb + a00 + dy8192 + dx128);
                if (l == 0) { g.wy0 = w.x; g.wz0 = w.y; }
                else        { g.wy1 = w.x; g.wz1 = w.y; }
            }
        }
        return g;
    };
    auto storePair = [&](int p, GP& g) {
#pragma unroll
        for (int l = 0; l < 2; ++l) {
            int tap = 2 * p + l;
            if (tap < 9) {
                union { unsigned u; __half2 h; } cy, cz;
                cy.u = l ? g.wy1 : g.wy0;
                cz.u = l ? g.wz1 : g.wz0;
                __half2 W00 = __half2half2(__low2half(cy.h));
                __half2 W01 = __half2half2(__high2half(cy.h));
                __half2 W10 = __half2half2(__low2half(cz.h));
                __half2 W11 = __half2half2(__high2half(cz.h));
                H8 res;
#pragma unroll
                for (int c = 0; c < 4; ++c) {
                    __half2 aa = __hmul2(g.v[4 * l + 0].h2[c], W00);
                    aa = __hfma2(g.v[4 * l + 1].h2[c], W01, aa);
                    aa = __hfma2(g.v[4 * l + 2].h2[c], W10, aa);
                    aa = __hfma2(g.v[4 * l + 3].h2[c], W11, aa);
                    res.h2[c] = aa;
                }
                *(half8*)&cols[gpx * CS9 + tap * 64 + oct * 8] = res.v;
            }
        }
    };

    {
        GP gcur = loadPair(0);
#pragma unroll
        for (int p = 0; p < 5; ++p) {
            GP gn;
            if (p < 4) gn = loadPair(p + 1);    // in flight over storePair(p)
            storePair(p, gcur);
            if (p < 4) gcur = gn;
        }
    }
    __syncthreads();

    // ---------------- straight MFMA loop (no barriers) -------------------
    auto loadW = [&](int i) -> half8 {
        return *(const half8*)&w2t[(size_t)i * 2048 + (wid * 16 + r) * 32 + q * 8];
    };

    floatx4 acc0 = {0.f, 0.f, 0.f, 0.f};
    floatx4 acc1 = {0.f, 0.f, 0.f, 0.f};
    half8 wfc = loadW(0);
#pragma unroll
    for (int i = 0; i < 18; ++i) {
        half8 wfn;
        if (i < 17) wfn = loadW(i + 1);
        half8 b0 = *(const half8*)&cols[r * CS9 + i * 32 + q * 8];
        half8 b1 = *(const half8*)&cols[(16 + r) * CS9 + i * 32 + q * 8];
        acc0 = __builtin_amdgcn_mfma_f32_16x16x32_f16(wfc, b0, acc0, 0, 0, 0);
        acc1 = __builtin_amdgcn_mfma_f32_16x16x32_f16(wfc, b1, acc1, 0, 0, 0);
        if (i < 17) wfc = wfn;
    }

    // ---------------- epilogue -------------------------------------------
#pragma unroll
    for (int reg = 0; reg < 4; ++reg) {
        int co = wid * 16 + q * 4 + reg;
        float bias = b_dcn[co];
        size_t o = (((size_t)b * 64 + co) * 64 + ho) * 64 + pxg;
        out[o + r]      = acc0[reg] + bias;
        out[o + 16 + r] = acc1[reg] + bias;
    }
}

// ---------------------------------------------------------------------------
// Fallback (R11-proven, x f32 direct) used only if ws too small.
#define FCPAD 40
__launch_bounds__(256, 4)
__global__ void dcn_fb(const float* __restrict__ x,
                       const float* __restrict__ w_dcn,
                       const float* __restrict__ w_off,
                       const float* __restrict__ b_off,
                       const float* __restrict__ b_dcn,
                       float* __restrict__ out) {
    const int bid = blockIdx.x;
    const int s   = bid >> 3;
    const int b   = ((bid & 7) << 1) | (s >> 7);
    const int ho  = (s >> 1) & 63;
    const int hlf = s & 1;
    const int t    = threadIdx.x;
    const int lane = t & 63;
    const int wid  = __builtin_amdgcn_readfirstlane(t >> 6);
    const int r    = lane & 15;
    const int q    = lane >> 4;
    const int px   = t & 31;
    const int kq   = t >> 5;

    __shared__ __align__(16) _Float16 colsT[2][32 * FCPAD];
    __shared__ __align__(16) float    offlds[KOFF * 32];

    const float* xb = x + (size_t)b * 64 * 4096;
    const int pxg = hlf * 32;

    {
        floatx4 am = {0.f, 0.f, 0.f, 0.f};
        const int m = wid & 1, n = wid >> 1;
        auto stageA = [&](int i) {
            const int tap = i >> 1;
            const int dy = tap / 3, dxk = tap - dy * 3;
            const int y  = ho + dy - 1;
            const int xc = pxg + px + dxk - 1;
            const bool ok = ((unsigned)y < 64u) && ((unsigned)xc < 64u);
            const float* xp = xb + ((size_t)((i & 1) * 32 + kq * 4)) * 4096
                                 + y * 64 + xc;
            float va[4];
#pragma unroll
            for (int j = 0; j < 4; ++j) va[j] = ok ? xp[(size_t)j * 4096] : 0.f;
#pragma unroll
            for (int j = 0; j < 4; ++j)
                colsT[i & 1][px * FCPAD + kq * 4 + j] = (_Float16)va[j];
        };
        auto loadA = [&](int i) -> half8 {
            const int tap = i >> 1;
            const int cin0 = (i & 1) * 32 + q * 8;
            const int co = m * 16 + r;
            half8 v;
#pragma unroll
            for (int j = 0; j < 8; ++j)
                v[j] = (co < KOFF) ? (_Float16)w_off[co * 576 + (cin0 + j) * 9 + tap]
                                   : (_Float16)0.f;
            return v;
        };
        stageA(0);
        __syncthreads();
#pragma unroll
        for (int i = 0; i < 18; ++i) {
            if (i < 17) stageA(i + 1);
            half8 a = loadA(i);
            half8 bfr = *(const half8*)&colsT[i & 1][(n * 16 + r) * FCPAD + q * 8];
            am = __builtin_amdgcn_mfma_f32_16x16x32_f16(a, bfr, am, 0, 0, 0);
            __syncthreads();
        }
#pragma unroll
        for (int reg = 0; reg < 4; ++reg) {
            int co = m * 16 + q * 4 + reg;
            if (co < KOFF)
                offlds[co * 32 + (n * 16 + r)] = am[reg] + b_off[co];
        }
    }
    __syncthreads();

    unsigned rmeta[9], rw0[9], rw1[9];
#pragma unroll
    for (int tap = 0; tap < 9; ++tap) {
        float offy = offlds[(2 * tap) * 32 + px];
        float offx = offlds[(2 * tap + 1) * 32 + px];
        float py  = offy + (float)(tap / 3) + (float)(ho - 1);
        float pxf = offx + (float)(tap % 3) + (float)(pxg + px - 1);
        float fy = floorf(py), fx = floorf(pxf);
        int y0 = (int)fy, x0 = (int)fx;
        float wy1 = py - fy, wx1 = pxf - fx;
        float wy0 = 1.f - wy1, wx0 = 1.f - wx1;
        bool y0ok = ((unsigned)y0 < 64u);
        bool x0ok = ((unsigned)x0 < 64u);
        bool y1ok = ((unsigned)(y0 + 1) < 64u);
        bool x1ok = ((unsigned)(x0 + 1) < 64u);
        float w00 = (y0ok && x0ok) ? wy0 * wx0 : 0.f;
        float w01 = (y0ok && x1ok) ? wy0 * wx1 : 0.f;
        float w10 = (y1ok && x0ok) ? wy1 * wx0 : 0.f;
        float w11 = (y1ok && x1ok) ? wy1 * wx1 : 0.f;
        int yc0 = min(max(y0, 0), 63);
        int xc0 = min(max(x0, 0), 63);
        int yc1 = min(max(y0 + 1, 0), 63);
        int xc1 = min(max(x0 + 1, 0), 63);
        union { __half2 h; unsigned u; } c0, c1;
        c0.h = __floats2half2_rn(w00, w01);
        c1.h = __floats2half2_rn(w10, w11);
        rmeta[tap] = (unsigned)(yc0 * 64 + xc0)
                   | ((unsigned)(xc1 - xc0) << 12)
                   | ((unsigned)(yc1 - yc0) << 13);
        rw0[tap] = c0.u;
        rw1[tap] = c1.u;
    }

    floatx4 acc0 = {0.f, 0.f, 0.f, 0.f};
    floatx4 acc1 = {0.f, 0.f, 0.f, 0.f};

    auto gather = [&](int i) {
        const int tap = i >> 1;
        const unsigned m = rmeta[tap];
        const unsigned a00 = (m & 0xfffu) << 2;
        const unsigned a01 = a00 + ((m >> 10) & 4u);
        const unsigned a10 = a00 + ((m >> 5) & 256u);
        const unsigned a11 = a10 + ((m >> 10) & 4u);
        const char* base = (const char*)xb
                         + ((size_t)((i & 1) * 32 + kq * 4)) * 16384;
        float v00[4], v01[4], v10[4], v11[4];
#pragma unroll
        for (int j = 0; j < 4; ++j) {
            const char* xp = base + (size_t)j * 16384;
            v00[j] = *(const float*)(xp + a00);
            v01[j] = *(const float*)(xp + a01);
            v10[j] = *(const float*)(xp + a10);
            v11[j] = *(const float*)(xp + a11);
        }
        union { unsigned u; __half2 h; } c0, c1;
        c0.u = rw0[tap]; c1.u = rw1[tap];
        const float wA = __half2float(c0.h.x), wB = __half2float(c0.h.y);
        const float wC = __half2float(c1.h.x), wD = __half2float(c1.h.y);
#pragma unroll
        for (int j = 0; j < 4; ++j)
            colsT[i & 1][px * FCPAD + kq * 4 + j] =
                (_Float16)(v00[j] * wA + v01[j] * wB + v10[j] * wC + v11[j] * wD);
    };

    auto load_af = [&](int i) -> half8 {
        const int tap = i >> 1;
        const int cin0 = (i & 1) * 32 + q * 8;
        half8 v;
#pragma unroll
        for (int j = 0; j < 8; ++j)
            v[j] = (_Float16)w_dcn[(wid * 16 + r) * 576 + (cin0 + j) * 9 + tap];
        return v;
    };

    gather(0);
    __syncthreads();
#pragma unroll
    for (int i = 0; i < 18; ++i) {
        if (i < 17) gather(i + 1);
        half8 af = load_af(i);
        half8 b0 = *(const half8*)&colsT[i & 1][r * FCPAD + q * 8];
        half8 b1 = *(const half8*)&colsT[i & 1][(16 + r) * FCPAD + q * 8];
        acc0 = __builtin_amdgcn_mfma_f32_16x16x32_f16(af, b0, acc0, 0, 0, 0);
        acc1 = __builtin_amdgcn_mfma_f32_16x16x32_f16(af, b1, acc1, 0, 0, 0);
        if (i < 17) __syncthreads();
    }

#pragma unroll
    for (int reg = 0; reg < 4; ++reg) {
        int co = wid * 16 + q * 4 + reg;
        float bias = b_dcn[co];
        size_t o = (((size_t)b * 64 + co) * 64 + ho) * 64 + pxg;
        out[o + r]      = acc0[reg] + bias;
        out[o + 16 + r] = acc1[reg] + bias;
    }
}

// ---------------------------------------------------------------------------
extern "C" void kernel_launch(void* const* d_in, const int* in_sizes, int n_in,
                              void* d_out, int out_size, void* d_ws, size_t ws_size,
                              hipStream_t stream) {
    const float* x     = (const float*)d_in[0];
    const float* w_off = (const float*)d_in[1];
    const float* b_off = (const float*)d_in[2];
    const float* w_dcn = (const float*)d_in[3];
    const float* b_dcn = (const float*)d_in[4];
    float* out = (float*)d_out;

    char* ws = (char*)d_ws;
    _Float16* w2t    = (_Float16*)ws;
    _Float16* woff2t = (_Float16*)(ws + WOFF2T_OFF);
    _Float16* xh     = (_Float16*)(ws + X_OFF);
    unsigned int* gm = (unsigned int*)(ws + GM_OFF);
    uint2*        gw = (uint2*)(ws + GW_OFF);

    if (ws_size >= (size_t)WS_NEED) {
        prep<<<1240, 256, 0, stream>>>(x, w_dcn, w_off, w2t, woff2t, xh);
        offs_k<<<2048, 256, 0, stream>>>(xh, woff2t, b_off, gm, gw);
        dcn_main<<<2048, 256, 0, stream>>>(xh, w2t, gm, gw, b_dcn, out);
    } else {
        dcn_fb<<<2048, 256, 0, stream>>>(x, w_dcn, w_off, b_off, b_dcn, out);
    }
}

// Round 3
// 104.490 us; speedup vs baseline: 1.0608x; 1.0608x over previous
//
#include <hip/hip_runtime.h>
#include <hip/hip_fp16.h>

// DeformConv2d: B=16, Cin=64, Cout=64, H=W=64, K=3, stride=1, pad=1, dil=1
// Round 19: L3-traffic collapse. R17 (schedule) and R18 (barrier structure)
// were both neutral -> kernels are Infinity-Cache-BW-bound (R15 datapoint:
// +75MB scattered reads cost +6us => ~12.5 TB/s marginal). This round stages
// a 5x37x64cin f16 halo of xh in LDS once per block (23.7KB); phase A reads
// B-frags straight from the halo, phase B gathers bilinear corners from the
// halo (box-checked; rare out-of-box offsets take the original global path).
// xh L3 reads: ~377MB -> ~49MB. Arithmetic order unchanged -> bit-identical.

#define KOFF 18
#define HROWS 5
#define HCOLS 37
#define HALO_HALFS (HROWS * HCOLS * 64)   // 11840 halfs = 23680 B
#define CS3 192                            // cols chunk stride (3 taps)

#define W2T_HALFS    (18 * 64 * 32)     // [i][64co][32kl], k' = tap*64+cin
#define WOFF2T_HALFS (18 * 32 * 32)     // [i][32co][32kl]
#define W2T_BYTES    (W2T_HALFS * 2)    // 73728
#define WOFF2T_OFF   W2T_BYTES
#define X_OFF        (W2T_BYTES + WOFF2T_HALFS * 2)   // 110592 (16B aligned)
#define XH_BYTES     (16 * 64 * 64 * 64 * 2)          // 8388608
#define WS_NEED      (X_OFF + XH_BYTES)               // 8499200

typedef _Float16 half8 __attribute__((ext_vector_type(8)));
typedef float floatx4 __attribute__((ext_vector_type(4)));

union H8 { half8 v; __half2 h2[4]; uint4 u; };

// ---------------------------------------------------------------------------
// prep: blocks [0,1024): LDS-tiled transpose of one (b,y) plane (coalesced
// both sides). blocks [1024,1240): weight repack (tap-major f16).
__global__ void prep(const float* __restrict__ x,
                     const float* __restrict__ w_dcn,
                     const float* __restrict__ w_off,
                     _Float16* __restrict__ w2t,
                     _Float16* __restrict__ woff2t,
                     _Float16* __restrict__ xh) {
    const int bi = blockIdx.x;
    const int t  = threadIdx.x;
    if (bi < 1024) {
        const int b = bi >> 6, y = bi & 63;
        __shared__ __align__(16) _Float16 tile[64 * 72];
        const int xx = t & 63;
        const int c4 = t >> 6;
        const float* xp = x + (((size_t)b * 64) * 64 + y) * 64;
#pragma unroll
        for (int p = 0; p < 16; ++p) {
            int cin = p * 4 + c4;
            tile[xx * 72 + cin] = (_Float16)xp[(size_t)cin * 4096 + xx];
        }
        __syncthreads();
        const int oct = t & 7;
        const int xl  = t >> 3;
        _Float16* op = xh + ((((size_t)b * 64 + y) * 64) << 6);
#pragma unroll
        for (int p = 0; p < 2; ++p) {
            int xr = p * 32 + xl;
            half8 v = *(const half8*)&tile[xr * 72 + oct * 8];
            *(half8*)&op[(size_t)xr * 64 + oct * 8] = v;
        }
    } else {
        int e = (bi - 1024) * 256 + t;
        if (e < W2T_HALFS) {
            int kl = e & 31, co = (e >> 5) & 63, i = e >> 11;
            int tap = i >> 1, cin = (i & 1) * 32 + kl;
            w2t[e] = (_Float16)w_dcn[co * 576 + cin * 9 + tap];
        } else {
            int e2 = e - W2T_HALFS;
            int kl = e2 & 31, co = (e2 >> 5) & 31, i = e2 >> 10;
            int tap = i >> 1, cin = (i & 1) * 32 + kl;
            woff2t[e2] = (co < KOFF) ? (_Float16)w_off[co * 576 + cin * 9 + tap]
                                     : (_Float16)0.f;
        }
    }
}

// ---------------------------------------------------------------------------
// dcn_one: halo-staged offset conv + geometry + gather + GEMM in one kernel.
__launch_bounds__(256, 4)
__global__ void dcn_one(const _Float16* __restrict__ xh,
                        const _Float16* __restrict__ w2t,
                        const _Float16* __restrict__ woff2t,
                        const float* __restrict__ b_off,
                        const float* __restrict__ b_dcn,
                        float* __restrict__ out) {
    const int bid = blockIdx.x;                 // 0..2047
    const int s   = bid >> 3;
    const int b   = ((bid & 7) << 1) | (s >> 7);
    const int ho  = (s >> 1) & 63;
    const int hlf = s & 1;
    const int t    = threadIdx.x;
    const int lane = t & 63;
    const int wid  = __builtin_amdgcn_readfirstlane(t >> 6);
    const int r    = lane & 15;
    const int q    = lane >> 4;
    const int gpx  = t >> 3;                    // 0..31 gather pixel
    const int oct  = t & 7;                     // 8-cin octet
    const int pxg  = hlf * 32;

    // LDS: halo 23680 + cols 12288 + meta 1152 + weights 2304 = 39424 B
    __shared__ __align__(16) _Float16 haloL[HALO_HALFS];
    __shared__ __align__(16) _Float16 colsL[32 * CS3];
    __shared__ __align__(16) unsigned int gmetaL[288];
    __shared__ __align__(16) uint2        gwL[288];
    float* offlds = (float*)colsL;              // overlay: used before cols

    const _Float16* xb = xh + ((size_t)b << 18);
    const char* xpb = (const char*)xb;

    // ---- 1. stage halo: rows ho-2..ho+2, cols pxg-2..pxg+34, swizzled ----
    // 16B slot s at (hy,hx) holds cin-octet (s ^ (hx&7)); OOB zero-filled.
    for (int e = t; e < HROWS * HCOLS * 8; e += 256) {
        int sl   = e & 7;
        int rest = e >> 3;                      // hy*37 + hx
        int hx = rest % HCOLS;
        int hy = rest / HCOLS;
        int y = ho - 2 + hy;
        int xx = pxg - 2 + hx;
        half8 v = {};
        if (((unsigned)y < 64u) && ((unsigned)xx < 64u)) {
            int oc = sl ^ (hx & 7);
            v = *(const half8*)&xb[(((size_t)(y * 64 + xx)) << 6) + oc * 8];
        }
        *(half8*)&haloL[(size_t)(rest * 8 + sl) * 8] = v;
    }
    __syncthreads();

    // ---- 2. phase A: offset conv, B-frags straight from halo -------------
    {
        floatx4 am = {0.f, 0.f, 0.f, 0.f};
        const int m = wid & 1, n = wid >> 1;
#pragma unroll
        for (int i = 0; i < 18; ++i) {
            const int tap = i >> 1, ch = i & 1;
            const int hy = tap / 3 + 1;                 // y = ho + dy - 1
            const int px = n * 16 + r;
            const int hx = px + (tap % 3) + 1;          // x = pxg+px+dxk-1
            const int sl = (ch * 4 + q) ^ (hx & 7);
            half8 bf = *(const half8*)&haloL[((hy * HCOLS + hx) * 8 + sl) * 8];
            half8 a  = *(const half8*)&woff2t[i * 1024 + (m * 16 + r) * 32 + q * 8];
            am = __builtin_amdgcn_mfma_f32_16x16x32_f16(a, bf, am, 0, 0, 0);
        }
#pragma unroll
        for (int reg = 0; reg < 4; ++reg) {
            int co = m * 16 + q * 4 + reg;
            if (co < KOFF)
                offlds[co * 32 + n * 16 + r] = am[reg] + b_off[co];
        }
    }
    __syncthreads();

    // ---- 3. geometry records (identical weight arithmetic) ---------------
    for (int e = t; e < 9 * 32; e += 256) {
        int tap = e >> 5, px = e & 31;
        float offy = offlds[(2 * tap) * 32 + px];
        float offx = offlds[(2 * tap + 1) * 32 + px];
        float py  = offy + (float)(tap / 3) + (float)(ho - 1);
        float pxf = offx + (float)(tap % 3) + (float)(pxg + px - 1);
        float fy = floorf(py), fx = floorf(pxf);
        int y0 = (int)fy, x0 = (int)fx;
        float wy1 = py - fy, wx1 = pxf - fx;
        float wy0 = 1.f - wy1, wx0 = 1.f - wx1;
        bool y0ok = ((unsigned)y0 < 64u);
        bool x0ok = ((unsigned)x0 < 64u);
        bool y1ok = ((unsigned)(y0 + 1) < 64u);
        bool x1ok = ((unsigned)(x0 + 1) < 64u);
        float w00 = (y0ok && x0ok) ? wy0 * wx0 : 0.f;
        float w01 = (y0ok && x1ok) ? wy0 * wx1 : 0.f;
        float w10 = (y1ok && x0ok) ? wy1 * wx0 : 0.f;
        float w11 = (y1ok && x1ok) ? wy1 * wx1 : 0.f;
        int yc0 = min(max(y0, 0), 63);
        int xc0 = min(max(x0, 0), 63);
        int yc1 = min(max(y0 + 1, 0), 63);
        int xc1 = min(max(x0 + 1, 0), 63);
        union { __half2 h; unsigned u; } c0, c1;
        c0.h = __floats2half2_rn(w00, w01);
        c1.h = __floats2half2_rn(w10, w11);
        // fast path iff all (clamped) corners live inside the staged halo box
        bool fast = (yc0 >= ho - 2) && (yc1 <= ho + 2)
                 && (xc0 >= pxg - 2) && (xc1 <= pxg + 34);
        unsigned meta;
        if (fast) {
            unsigned hy0 = (unsigned)(yc0 - (ho - 2));
            unsigned hx0 = (unsigned)(xc0 - (pxg - 2));
            meta = 0x80000000u | hx0 | (hy0 << 8)
                 | ((unsigned)(xc1 - xc0) << 16)
                 | ((unsigned)(yc1 - yc0) << 17);
        } else {
            meta = (unsigned)(yc0 * 64 + xc0)
                 | ((unsigned)(xc1 - xc0) << 12)
                 | ((unsigned)(yc1 - yc0) << 13);
        }
        gmetaL[e] = meta;
        gwL[e]    = make_uint2(c0.u, c1.u);
    }
    __syncthreads();

    // ---- 4. phase B: 3 chunks of 3 taps; gather from halo LDS ------------
    floatx4 acc0 = {0.f, 0.f, 0.f, 0.f};
    floatx4 acc1 = {0.f, 0.f, 0.f, 0.f};

#pragma unroll
    for (int c = 0; c < 3; ++c) {
        // gather + combine 3 taps for pixel gpx, octet oct
#pragma unroll
        for (int u3 = 0; u3 < 3; ++u3) {
            const int tap = c * 3 + u3;
            unsigned meta = gmetaL[tap * 32 + gpx];
            uint2    wr   = gwL[tap * 32 + gpx];
            H8 v00, v01, v10, v11;
            if (meta & 0x80000000u) {
                int hx0 = (int)(meta & 63u);
                int hy0 = (int)((meta >> 8) & 7u);
                int dx  = (int)((meta >> 16) & 1u);
                int dy  = (int)((meta >> 17) & 1u);
                int b0i = hy0 * HCOLS + hx0;
                int s0  = oct ^ (hx0 & 7);
                int s1  = oct ^ ((hx0 + dx) & 7);
                v00.v = *(const half8*)&haloL[(b0i * 8 + s0) * 8];
                v01.v = *(const half8*)&haloL[((b0i + dx) * 8 + s1) * 8];
                v10.v = *(const half8*)&haloL[((b0i + dy * HCOLS) * 8 + s0) * 8];
                v11.v = *(const half8*)&haloL[((b0i + dy * HCOLS + dx) * 8 + s1) * 8];
            } else {
                unsigned a00 = (meta & 0xfffu) * 128u + (unsigned)oct * 16u;
                unsigned dx128  = ((meta >> 12) & 1u) * 128u;
                unsigned dy8192 = ((meta >> 13) & 1u) * 8192u;
                v00.v = *(const half8*)(xpb + a00);
                v01.v = *(const half8*)(xpb + a00 + dx128);
                v10.v = *(const half8*)(xpb + a00 + dy8192);
                v11.v = *(const half8*)(xpb + a00 + dy8192 + dx128);
            }
            union { unsigned u; __half2 h; } cy, cz;
            cy.u = wr.x;
            cz.u = wr.y;
            __half2 W00 = __half2half2(__low2half(cy.h));
            __half2 W01 = __half2half2(__high2half(cy.h));
            __half2 W10 = __half2half2(__low2half(cz.h));
            __half2 W11 = __half2half2(__high2half(cz.h));
            H8 res;
#pragma unroll
            for (int cc = 0; cc < 4; ++cc) {
                __half2 aa = __hmul2(v00.h2[cc], W00);
                aa = __hfma2(v01.h2[cc], W01, aa);
                aa = __hfma2(v10.h2[cc], W10, aa);
                aa = __hfma2(v11.h2[cc], W11, aa);
                res.h2[cc] = aa;
            }
            *(half8*)&colsL[gpx * CS3 + u3 * 64 + (oct ^ (gpx & 7)) * 8] = res.v;
        }
        // weight prefetch overlaps the barrier
        half8 wf6[6];
#pragma unroll
        for (int u = 0; u < 6; ++u)
            wf6[u] = *(const half8*)&w2t[(size_t)(c * 6 + u) * 2048
                                         + (wid * 16 + r) * 32 + q * 8];
        __syncthreads();
#pragma unroll
        for (int u = 0; u < 6; ++u) {
            const int u3 = u >> 1, ch = u & 1;
            const int sl = (ch * 4 + q) ^ (r & 7);     // (16+r)&7 == r&7
            half8 b0 = *(const half8*)&colsL[r * CS3 + u3 * 64 + sl * 8];
            half8 b1 = *(const half8*)&colsL[(16 + r) * CS3 + u3 * 64 + sl * 8];
            acc0 = __builtin_amdgcn_mfma_f32_16x16x32_f16(wf6[u], b0, acc0, 0, 0, 0);
            acc1 = __builtin_amdgcn_mfma_f32_16x16x32_f16(wf6[u], b1, acc1, 0, 0, 0);
        }
        if (c < 2) __syncthreads();
    }

    // ---- epilogue --------------------------------------------------------
#pragma unroll
    for (int reg = 0; reg < 4; ++reg) {
        int co = wid * 16 + q * 4 + reg;
        float bias = b_dcn[co];
        size_t o = (((size_t)b * 64 + co) * 64 + ho) * 64 + pxg;
        out[o + r]      = acc0[reg] + bias;
        out[o + 16 + r] = acc1[reg] + bias;
    }
}

// ---------------------------------------------------------------------------
// Fallback (R11-proven, x f32 direct) used only if ws too small.
#define FCPAD 40
__launch_bounds__(256, 4)
__global__ void dcn_fb(const float* __restrict__ x,
                       const float* __restrict__ w_dcn,
                       const float* __restrict__ w_off,
                       const float* __restrict__ b_off,
                       const float* __restrict__ b_dcn,
                       float* __restrict__ out) {
    const int bid = blockIdx.x;
    const int s   = bid >> 3;
    const int b   = ((bid & 7) << 1) | (s >> 7);
    const int ho  = (s >> 1) & 63;
    const int hlf = s & 1;
    const int t    = threadIdx.x;
    const int lane = t & 63;
    const int wid  = __builtin_amdgcn_readfirstlane(t >> 6);
    const int r    = lane & 15;
    const int q    = lane >> 4;
    const int px   = t & 31;
    const int kq   = t >> 5;

    __shared__ __align__(16) _Float16 colsT[2][32 * FCPAD];
    __shared__ __align__(16) float    offlds[KOFF * 32];

    const float* xb = x + (size_t)b * 64 * 4096;
    const int pxg = hlf * 32;

    {
        floatx4 am = {0.f, 0.f, 0.f, 0.f};
        const int m = wid & 1, n = wid >> 1;
        auto stageA = [&](int i) {
            const int tap = i >> 1;
            const int dy = tap / 3, dxk = tap - dy * 3;
            const int y  = ho + dy - 1;
            const int xc = pxg + px + dxk - 1;
            const bool ok = ((unsigned)y < 64u) && ((unsigned)xc < 64u);
            const float* xp = xb + ((size_t)((i & 1) * 32 + kq * 4)) * 4096
                                 + y * 64 + xc;
            float va[4];
#pragma unroll
            for (int j = 0; j < 4; ++j) va[j] = ok ? xp[(size_t)j * 4096] : 0.f;
#pragma unroll
            for (int j = 0; j < 4; ++j)
                colsT[i & 1][px * FCPAD + kq * 4 + j] = (_Float16)va[j];
        };
        auto loadA = [&](int i) -> half8 {
            const int tap = i >> 1;
            const int cin0 = (i & 1) * 32 + q * 8;
            const int co = m * 16 + r;
            half8 v;
#pragma unroll
            for (int j = 0; j < 8; ++j)
                v[j] = (co < KOFF) ? (_Float16)w_off[co * 576 + (cin0 + j) * 9 + tap]
                                   : (_Float16)0.f;
            return v;
        };
        stageA(0);
        __syncthreads();
#pragma unroll
        for (int i = 0; i < 18; ++i) {
            if (i < 17) stageA(i + 1);
            half8 a = loadA(i);
            half8 bfr = *(const half8*)&colsT[i & 1][(n * 16 + r) * FCPAD + q * 8];
            am = __builtin_amdgcn_mfma_f32_16x16x32_f16(a, bfr, am, 0, 0, 0);
            __syncthreads();
        }
#pragma unroll
        for (int reg = 0; reg < 4; ++reg) {
            int co = m * 16 + q * 4 + reg;
            if (co < KOFF)
                offlds[co * 32 + (n * 16 + r)] = am[reg] + b_off[co];
        }
    }
    __syncthreads();

    unsigned rmeta[9], rw0[9], rw1[9];
#pragma unroll
    for (int tap = 0; tap < 9; ++tap) {
        float offy = offlds[(2 * tap) * 32 + px];
        float offx = offlds[(2 * tap + 1) * 32 + px];
        float py  = offy + (float)(tap / 3) + (float)(ho - 1);
        float pxf = offx + (float)(tap % 3) + (float)(pxg + px - 1);
        float fy = floorf(py), fx = floorf(pxf);
        int y0 = (int)fy, x0 = (int)fx;
        float wy1 = py - fy, wx1 = pxf - fx;
        float wy0 = 1.f - wy1, wx0 = 1.f - wx1;
        bool y0ok = ((unsigned)y0 < 64u);
        bool x0ok = ((unsigned)x0 < 64u);
        bool y1ok = ((unsigned)(y0 + 1) < 64u);
        bool x1ok = ((unsigned)(x0 + 1) < 64u);
        float w00 = (y0ok && x0ok) ? wy0 * wx0 : 0.f;
        float w01 = (y0ok && x1ok) ? wy0 * wx1 : 0.f;
        float w10 = (y1ok && x0ok) ? wy1 * wx0 : 0.f;
        float w11 = (y1ok && x1ok) ? wy1 * wx1 : 0.f;
        int yc0 = min(max(y0, 0), 63);
        int xc0 = min(max(x0, 0), 63);
        int yc1 = min(max(y0 + 1, 0), 63);
        int xc1 = min(max(x0 + 1, 0), 63);
        union { __half2 h; unsigned u; } c0, c1;
        c0.h = __floats2half2_rn(w00, w01);
        c1.h = __floats2half2_rn(w10, w11);
        rmeta[tap] = (unsigned)(yc0 * 64 + xc0)
                   | ((unsigned)(xc1 - xc0) << 12)
                   | ((unsigned)(yc1 - yc0) << 13);
        rw0[tap] = c0.u;
        rw1[tap] = c1.u;
    }

    floatx4 acc0 = {0.f, 0.f, 0.f, 0.f};
    floatx4 acc1 = {0.f, 0.f, 0.f, 0.f};

    auto gather = [&](int i) {
        const int tap = i >> 1;
        const unsigned m = rmeta[tap];
        const unsigned a00 = (m & 0xfffu) << 2;
        const unsigned a01 = a00 + ((m >> 10) & 4u);
        const unsigned a10 = a00 + ((m >> 5) & 256u);
        const unsigned a11 = a10 + ((m >> 10) & 4u);
        const char* base = (const char*)xb
                         + ((size_t)((i & 1) * 32 + kq * 4)) * 16384;
        float v00[4], v01[4], v10[4], v11[4];
#pragma unroll
        for (int j = 0; j < 4; ++j) {
            const char* xp = base + (size_t)j * 16384;
            v00[j] = *(const float*)(xp + a00);
            v01[j] = *(const float*)(xp + a01);
            v10[j] = *(const float*)(xp + a10);
            v11[j] = *(const float*)(xp + a11);
        }
        union { unsigned u; __half2 h; } c0, c1;
        c0.u = rw0[tap]; c1.u = rw1[tap];
        const float wA = __half2float(c0.h.x), wB = __half2float(c0.h.y);
        const float wC = __half2float(c1.h.x), wD = __half2float(c1.h.y);
#pragma unroll
        for (int j = 0; j < 4; ++j)
            colsT[i & 1][px * FCPAD + kq * 4 + j] =
                (_Float16)(v00[j] * wA + v01[j] * wB + v10[j] * wC + v11[j] * wD);
    };

    auto load_af = [&](int i) -> half8 {
        const int tap = i >> 1;
        const int cin0 = (i & 1) * 32 + q * 8;
        half8 v;
#pragma unroll
        for (int j = 0; j < 8; ++j)
            v[j] = (_Float16)w_dcn[(wid * 16 + r) * 576 + (cin0 + j) * 9 + tap];
        return v;
    };

    gather(0);
    __syncthreads();
#pragma unroll
    for (int i = 0; i < 18; ++i) {
        if (i < 17) gather(i + 1);
        half8 af = load_af(i);
        half8 b0 = *(const half8*)&colsT[i & 1][r * FCPAD + q * 8];
        half8 b1 = *(const half8*)&colsT[i & 1][(16 + r) * FCPAD + q * 8];
        acc0 = __builtin_amdgcn_mfma_f32_16x16x32_f16(af, b0, acc0, 0, 0, 0);
        acc1 = __builtin_amdgcn_mfma_f32_16x16x32_f16(af, b1, acc1, 0, 0, 0);
        if (i < 17) __syncthreads();
    }

#pragma unroll
    for (int reg = 0; reg < 4; ++reg) {
        int co = wid * 16 + q * 4 + reg;
        float bias = b_dcn[co];
        size_t o = (((size_t)b * 64 + co) * 64 + ho) * 64 + pxg;
        out[o + r]      = acc0[reg] + bias;
        out[o + 16 + r] = acc1[reg] + bias;
    }
}

// ---------------------------------------------------------------------------
extern "C" void kernel_launch(void* const* d_in, const int* in_sizes, int n_in,
                              void* d_out, int out_size, void* d_ws, size_t ws_size,
                              hipStream_t stream) {
    const float* x     = (const float*)d_in[0];
    const float* w_off = (const float*)d_in[1];
    const float* b_off = (const float*)d_in[2];
    const float* w_dcn = (const float*)d_in[3];
    const float* b_dcn = (const float*)d_in[4];
    float* out = (float*)d_out;

    char* ws = (char*)d_ws;
    _Float16* w2t    = (_Float16*)ws;
    _Float16* woff2t = (_Float16*)(ws + WOFF2T_OFF);
    _Float16* xh     = (_Float16*)(ws + X_OFF);

    if (ws_size >= (size_t)WS_NEED) {
        prep<<<1240, 256, 0, stream>>>(x, w_dcn, w_off, w2t, woff2t, xh);
        dcn_one<<<2048, 256, 0, stream>>>(xh, w2t, woff2t, b_off, b_dcn, out);
    } else {
        dcn_fb<<<2048, 256, 0, stream>>>(x, w_dcn, w_off, b_off, b_dcn, out);
    }
}